// Round 16
// baseline (136.388 us; speedup 1.0000x reference)
//
#include <hip/hip_runtime.h>

#define NDAYS 250
#define SCALING 12.0f
#define TPB 256
#define TILE 1024      // samples per tile; 1280 f4 chunks = 5/thread
#define MIDB 64
#define RPM 16         // rows per mid block (64*16=1024 >= 978)

typedef float f4 __attribute__((ext_vector_type(4)));

// Pi[d] = sum over k in [0,4N): w[k%N]*t_flat[k]*sigmoid(12*in_flat[k]) by date[k%N].
// k = 4i+j sample-major, i = q*nq+ii -> m = 4*ii+j.
// Q-SPLIT x2: tile (ii0..ii0+TILE) is handled by TWO blocks, qh=0 covers q{0,1}, qh=1
// covers q{2,3}. Day-sums add linearly, so each half scatters w*acc_half independently.
// Doubles resident waves (1.9 -> 3.8 per SIMD) for latency hiding; w/d read twice
// (second read ~L3-hit). Thread t owns f4 chunks {256e+t, e<5}: stream loads are
// lane-stride 16 B coalesced; metadata (m, day, weight) via direct gathers (R12-best).
// Invalid slots (col j==4 / tile tail): weight=0, day=lane (adds 0.0, lane-distinct).
__global__ __launch_bounds__(TPB) void pi_kernel(
    const float* __restrict__ inputs, const float* __restrict__ targets,
    const float* __restrict__ weights, const int* __restrict__ date,
    float* __restrict__ part, int n) {
    __shared__ float sPi[NDAYS];
    for (int i = threadIdx.x; i < NDAYS; i += TPB) sPi[i] = 0.0f;
    __syncthreads();

    const int nq  = n >> 2;
    const int ii0 = (blockIdx.x >> 1) * TILE;
    const int qh  = blockIdx.x & 1;
    const int lane = threadIdx.x & 63;

    const int ts  = min(TILE, nq - ii0);
    const int nfl = ts * 5;

    int   dy[5][4];
    float wt[5][4];
    #pragma unroll
    for (int e = 0; e < 5; ++e) {
        const int fl0 = 4 * (TPB * e + threadIdx.x);
        #pragma unroll
        for (int dlt = 0; dlt < 4; ++dlt) {
            const int fl = fl0 + dlt;
            const int si = (int)(((unsigned)fl * 52429u) >> 18);  // fl/5 exact for fl<5120
            const int j  = fl - 5 * si;
            const bool valid = (fl < nfl) && (j < 4);
            const int  m = valid ? (4 * (ii0 + si) + j) : 0;
            wt[e][dlt] = valid ? weights[m] : 0.0f;
            dy[e][dlt] = valid ? date[m] : lane;
        }
    }

    float acc[5][4] = {};
    #pragma unroll
    for (int qq = 0; qq < 2; ++qq) {
        const int q = 2 * qh + qq;
        const size_t base = ((size_t)q * nq + ii0) * 5;            // 16B-aligned
        #pragma unroll
        for (int e = 0; e < 5; ++e) {
            const int fl0 = 4 * (TPB * e + threadIdx.x);
            f4 inv = {0.0f, 0.0f, 0.0f, 0.0f};
            f4 tgv = {0.0f, 0.0f, 0.0f, 0.0f};
            if (fl0 < nfl) {
                inv = *(const f4*)(inputs + base + fl0);
                tgv = *(const f4*)(targets + base + fl0);
            }
            #pragma unroll
            for (int dlt = 0; dlt < 4; ++dlt) {
                const float e1 = __expf(-SCALING * inv[dlt]);
                const float sg = __builtin_amdgcn_rcpf(1.0f + e1);
                acc[e][dlt] += tgv[dlt] * sg;
            }
        }
    }

    #pragma unroll
    for (int e = 0; e < 5; ++e)
        #pragma unroll
        for (int dlt = 0; dlt < 4; ++dlt)
            atomicAdd(&sPi[dy[e][dlt]], acc[e][dlt] * wt[e][dlt]);

    __syncthreads();
    float* row = part + (size_t)blockIdx.x * NDAYS;
    for (int i = threadIdx.x; i < NDAYS; i += TPB) row[i] = sPi[i];
}

// 64 blocks: block b reduces part rows [b*RPM, min(b*RPM+RPM, nrows)) -> part2[b][250].
__global__ __launch_bounds__(TPB) void mid_kernel(const float* __restrict__ part,
                                                  float* __restrict__ part2, int nrows) {
    const int c = threadIdx.x;
    if (c < NDAYS) {
        const int r0 = blockIdx.x * RPM;
        const int r1 = min(r0 + RPM, nrows);
        float a = 0.0f;
        for (int r = r0; r < r1; ++r) a += part[(size_t)r * NDAYS + c];
        part2[(size_t)blockIdx.x * NDAYS + c] = a;
    }
}

// 1 block: Pi[c] = sum of MIDB rows of part2; then loss.
__global__ __launch_bounds__(TPB) void fin_kernel(const float* __restrict__ part2,
                                                  float* __restrict__ out) {
    __shared__ float ws_s[4], ws_q[4];
    const int t = threadIdx.x;
    float s = 0.0f, q = 0.0f;
    if (t < NDAYS) {
        float pc = 0.0f;
        #pragma unroll 8
        for (int r = 0; r < MIDB; ++r) pc += part2[(size_t)r * NDAYS + t];
        s = pc;
        q = pc * pc;
    }
    #pragma unroll
    for (int off = 32; off > 0; off >>= 1) {
        s += __shfl_down(s, off);
        q += __shfl_down(q, off);
    }
    if ((t & 63) == 0) {
        ws_s[t >> 6] = s;
        ws_q[t >> 6] = q;
    }
    __syncthreads();
    if (t == 0) {
        const float sumPi  = ws_s[0] + ws_s[1] + ws_s[2] + ws_s[3];
        const float sumPi2 = ws_q[0] + ws_q[1] + ws_q[2] + ws_q[3];
        out[0] = -1.0f * sumPi * fmaxf(sumPi, 0.0f) / sumPi2 / (float)NDAYS;
    }
}

extern "C" void kernel_launch(void* const* d_in, const int* in_sizes, int n_in,
                              void* d_out, int out_size, void* d_ws, size_t ws_size,
                              hipStream_t stream) {
    const float* inputs  = (const float*)d_in[0];
    const float* targets = (const float*)d_in[1];
    const float* weights = (const float*)d_in[2];
    const int*   date    = (const int*)d_in[3];
    float* out   = (float*)d_out;
    float* part  = (float*)d_ws;                       // nrows*NDAYS floats (<=1 MB)
    float* part2 = part + (size_t)1024 * NDAYS;        // MIDB*NDAYS floats

    const int n  = in_sizes[2];                        // N (weights is [N])
    const int nq = n >> 2;
    const int ntiles = (nq + TILE - 1) / TILE;         // 489 for N=2M
    const int grid = 2 * ntiles;                       // 978: q-split x2

    pi_kernel<<<grid, TPB, 0, stream>>>(inputs, targets, weights, date, part, n);
    mid_kernel<<<MIDB, TPB, 0, stream>>>(part, part2, grid);
    fin_kernel<<<1, TPB, 0, stream>>>(part2, out);
}

// Round 17
// 126.384 us; speedup vs baseline: 1.0792x; 1.0792x over previous
//
#include <hip/hip_runtime.h>

#define NDAYS 250
#define SCALING 12.0f
#define TPB 256
#define NBLK 512        // >= ceil(nq/TILE) = 489 supertiles; extras write zero rows
#define TILE 1024       // samples per q per supertile (TILE*5 = 5120 floats = 20*TPB f4 chunks)
#define MIDB 64
#define RPM (NBLK / MIDB)

typedef float f4 __attribute__((ext_vector_type(4)));

// Pi[d] = sum over k in [0,4N): w[k%N]*t_flat[k]*sigmoid(12*in_flat[k]) by date[k%N].
// k = 4i+j (sample-major), i = q*nq+ii -> m = k%N = 4*ii+j.
// COALESCED layout: block owns ii-tile of 1024 samples (all 4 q's). Thread t owns f4
// chunks {256e+t, e<5} of the 5120-float tile -> global loads are lane-stride 16 B.
// Chunk float positions are q-independent: metadata (m, day, weight, validity) computed
// once; acc[5][4] accumulates t*sigmoid across q in registers; one LDS atomic per element.
// Invalid elements (resp col j==4, or tail beyond tile): weight=0, day=lane (adds 0.0,
// lane-distinct so no same-address atomic serialization).
// [R12-best: 125.14 us total. R13 (LDS-staged w/d) 126.8, R16 (q-split x2) 136.4 — both
// regressions; reverted here.]
__global__ __launch_bounds__(TPB) void pi_kernel(
    const float* __restrict__ inputs, const float* __restrict__ targets,
    const float* __restrict__ weights, const int* __restrict__ date,
    float* __restrict__ part, int n) {
    __shared__ float sPi[NDAYS];
    for (int i = threadIdx.x; i < NDAYS; i += TPB) sPi[i] = 0.0f;
    __syncthreads();

    const int nq = n >> 2;                 // samples per q-segment
    const int ii0 = blockIdx.x * TILE;
    if (ii0 < nq) {
        const int ts  = min(TILE, nq - ii0);   // samples in this tile
        const int nfl = ts * 5;                // valid floats per array per q
        const int lane = threadIdx.x & 63;

        int   dy[5][4];
        float wt[5][4];
        #pragma unroll
        for (int e = 0; e < 5; ++e) {
            const int c   = TPB * e + threadIdx.x;  // chunk id in tile
            const int fl0 = 4 * c;
            #pragma unroll
            for (int dlt = 0; dlt < 4; ++dlt) {
                const int fl = fl0 + dlt;
                const int si = (int)(((unsigned)fl * 52429u) >> 18);  // fl/5 (exact, fl<5120)
                const int j  = fl - 5 * si;
                const bool valid = (fl < nfl) && (j < 4);
                const int  m = valid ? (4 * (ii0 + si) + j) : 0;
                wt[e][dlt] = valid ? weights[m] : 0.0f;
                dy[e][dlt] = valid ? date[m] : lane;
            }
        }

        float acc[5][4] = {};
        #pragma unroll
        for (int q = 0; q < 4; ++q) {
            const size_t base = ((size_t)q * nq + ii0) * 5;   // 16B-aligned
            #pragma unroll
            for (int e = 0; e < 5; ++e) {
                const int c = TPB * e + threadIdx.x;
                f4 inv = {0.0f, 0.0f, 0.0f, 0.0f};
                f4 tgv = {0.0f, 0.0f, 0.0f, 0.0f};
                if (4 * c < nfl) {
                    inv = *(const f4*)(inputs + base + 4 * c);
                    tgv = *(const f4*)(targets + base + 4 * c);
                }
                #pragma unroll
                for (int dlt = 0; dlt < 4; ++dlt) {
                    const float e1 = __expf(-SCALING * inv[dlt]);
                    const float sg = __builtin_amdgcn_rcpf(1.0f + e1);
                    acc[e][dlt] += tgv[dlt] * sg;
                }
            }
        }

        #pragma unroll
        for (int e = 0; e < 5; ++e)
            #pragma unroll
            for (int dlt = 0; dlt < 4; ++dlt)
                atomicAdd(&sPi[dy[e][dlt]], acc[e][dlt] * wt[e][dlt]);
    }

    __syncthreads();
    float* row = part + (size_t)blockIdx.x * NDAYS;
    for (int i = threadIdx.x; i < NDAYS; i += TPB) row[i] = sPi[i];
}

// 64 blocks: block b reduces part rows b*8..b*8+7 -> part2[b][250]. Coalesced (lane = col).
__global__ __launch_bounds__(TPB) void mid_kernel(const float* __restrict__ part,
                                                  float* __restrict__ part2) {
    const int c = threadIdx.x;
    if (c < NDAYS) {
        const float* p = part + (size_t)blockIdx.x * RPM * NDAYS + c;
        float a = 0.0f;
        #pragma unroll
        for (int r = 0; r < RPM; ++r) a += p[(size_t)r * NDAYS];
        part2[(size_t)blockIdx.x * NDAYS + c] = a;
    }
}

// 1 block: Pi[c] = sum of MIDB rows of part2; then loss.
__global__ __launch_bounds__(TPB) void fin_kernel(const float* __restrict__ part2,
                                                  float* __restrict__ out) {
    __shared__ float ws_s[4], ws_q[4];
    const int t = threadIdx.x;
    float s = 0.0f, q = 0.0f;
    if (t < NDAYS) {
        float pc = 0.0f;
        #pragma unroll 8
        for (int r = 0; r < MIDB; ++r) pc += part2[(size_t)r * NDAYS + t];
        s = pc;
        q = pc * pc;
    }
    #pragma unroll
    for (int off = 32; off > 0; off >>= 1) {
        s += __shfl_down(s, off);
        q += __shfl_down(q, off);
    }
    if ((t & 63) == 0) {
        ws_s[t >> 6] = s;
        ws_q[t >> 6] = q;
    }
    __syncthreads();
    if (t == 0) {
        const float sumPi  = ws_s[0] + ws_s[1] + ws_s[2] + ws_s[3];
        const float sumPi2 = ws_q[0] + ws_q[1] + ws_q[2] + ws_q[3];
        out[0] = -1.0f * sumPi * fmaxf(sumPi, 0.0f) / sumPi2 / (float)NDAYS;
    }
}

extern "C" void kernel_launch(void* const* d_in, const int* in_sizes, int n_in,
                              void* d_out, int out_size, void* d_ws, size_t ws_size,
                              hipStream_t stream) {
    const float* inputs  = (const float*)d_in[0];
    const float* targets = (const float*)d_in[1];
    const float* weights = (const float*)d_in[2];
    const int*   date    = (const int*)d_in[3];
    float* out   = (float*)d_out;
    float* part  = (float*)d_ws;                       // NBLK*NDAYS floats = 512 KB
    float* part2 = part + (size_t)NBLK * NDAYS;        // MIDB*NDAYS floats = 64 KB

    const int n = in_sizes[2];   // N (weights is [N])

    pi_kernel<<<NBLK, TPB, 0, stream>>>(inputs, targets, weights, date, part, n);
    mid_kernel<<<MIDB, TPB, 0, stream>>>(part, part2);
    fin_kernel<<<1, TPB, 0, stream>>>(part2, out);
}